// Round 1
// 428.691 us; speedup vs baseline: 1.0202x; 1.0202x over previous
//
#include <hip/hip_runtime.h>

// ResNet theta-step, elementwise closed iteration + scalar fmin reduction.
// x: (4096, 16384) fp32. out: same shape fp32, then one extra float = fmin.
//
// Per element (H=1, THETA=0.5, MAXNITER=10):
//   e   = x + 0.5*relu(x)
//   z0  = e;  z_{k+1} = e + 0.5*relu(z_k)   (10 iterations)
//   out = e + 0.5*relu(z10)
//   r   = z10 - e - 0.5*relu(z10)
//   fmin = 0.5 * sum(r^2)
//
// Memory-bound: 256 MiB in + 256 MiB out, floor ~85 us @ 6.3 TB/s.
// This version: software-pipelined grid-stride loop (prefetch next float4
// before computing current) + nontemporal loads/stores (512 MiB streamed
// once; don't let read/write streams thrash the 4 MiB/XCD L2).

#define THETA 0.5f
#define ONE_MINUS_THETA 0.5f
#define NITER 10

typedef float v4f __attribute__((ext_vector_type(4)));

__device__ __forceinline__ float process_one(float xv, float& acc) {
    float e = xv + ONE_MINUS_THETA * fmaxf(xv, 0.0f);   // H = 1
    float z = e;
#pragma unroll
    for (int it = 0; it < NITER; ++it) {
        z = e + THETA * fmaxf(z, 0.0f);
    }
    float rz = THETA * fmaxf(z, 0.0f);
    float o  = e + rz;
    float r  = z - e - rz;
    acc += 0.5f * r * r;
    return o;
}

__global__ __launch_bounds__(256) void resnet_step_kernel(
    const float* __restrict__ x, float* __restrict__ out,
    float* __restrict__ fmin_out, int n4)
{
    const v4f* __restrict__ x4 = (const v4f*)x;
    v4f* __restrict__ o4 = (v4f*)out;

    float local = 0.0f;
    const int stride = gridDim.x * blockDim.x;
    int i = blockIdx.x * blockDim.x + threadIdx.x;

    if (i < n4) {
        // software pipeline: keep one load in flight across the compute chain
        v4f v = __builtin_nontemporal_load(&x4[i]);
        int cur = i;
        int nxt = i + stride;
        for (;;) {
            const bool more = (nxt < n4);
            v4f vn;
            if (more) vn = __builtin_nontemporal_load(&x4[nxt]);  // issue early

            v4f o;
            o.x = process_one(v.x, local);
            o.y = process_one(v.y, local);
            o.z = process_one(v.z, local);
            o.w = process_one(v.w, local);
            __builtin_nontemporal_store(o, &o4[cur]);

            if (!more) break;
            v = vn;
            cur = nxt;
            nxt += stride;
        }
    }

    // wave-64 shuffle reduction
#pragma unroll
    for (int off = 32; off > 0; off >>= 1) {
        local += __shfl_down(local, off, 64);
    }

    __shared__ float s_partial[4];  // 256 threads = 4 waves
    const int lane = threadIdx.x & 63;
    const int wid  = threadIdx.x >> 6;
    if (lane == 0) s_partial[wid] = local;
    __syncthreads();
    if (threadIdx.x == 0) {
        float t = s_partial[0] + s_partial[1] + s_partial[2] + s_partial[3];
        atomicAdd(fmin_out, t);  // device-scope by default on CDNA
    }
}

extern "C" void kernel_launch(void* const* d_in, const int* in_sizes, int n_in,
                              void* d_out, int out_size, void* d_ws, size_t ws_size,
                              hipStream_t stream) {
    const float* x = (const float*)d_in[0];
    float* out = (float*)d_out;
    const int n = in_sizes[0];          // 4096*16384 = 67108864 (divisible by 4)
    float* fmin_out = out + n;          // out_size = n + 1

    // d_out is re-poisoned to 0xAA before every timed replay — zero the
    // accumulator slot ourselves (async memset is graph-capture legal).
    hipMemsetAsync(fmin_out, 0, sizeof(float), stream);

    const int n4 = n / 4;
    dim3 block(256);
    dim3 grid(2048);                    // 8 blocks/CU * 256 CUs = 32 waves/CU
    resnet_step_kernel<<<grid, block, 0, stream>>>(x, out, fmin_out, n4);
}